// Round 1
// baseline (145.675 us; speedup 1.0000x reference)
//
#include <hip/hip_runtime.h>
#include <hip/hip_bf16.h>

typedef float f32x4 __attribute__((ext_vector_type(4)));
typedef short bf16x8 __attribute__((ext_vector_type(8)));
typedef float float4v __attribute__((ext_vector_type(4)));

#define XS_STRIDE 296   // 288 k-window + 8 pad (keeps ds_read_b128 16B-aligned, ~2-way banks)
#define H1_STRIDE 40    // 32 + 8 pad
#define W1T_K 576
#define W2T_OFF (48 * 576)

__device__ __forceinline__ short f2bf(float f) {
  __bf16 b = (__bf16)f;
  return __builtin_bit_cast(short, b);
}
__device__ __forceinline__ float fast_sigmoid(float x) {
  return __builtin_amdgcn_rcpf(1.f + __expf(-x));
}
__device__ __forceinline__ float fast_tanh(float x) {
  float e = __expf(2.f * x);
  return 1.f - 2.f * __builtin_amdgcn_rcpf(e + 1.f);  // exact identity; saturates cleanly at +-1
}

// ---- prep: bf16 weight layouts in d_ws ----
// ws[0 .. 48*576)        : W1bT[n][k] = (n<32 ? W1[k][n] : n==32 ? Wr[k] : 0)   [fc1 B, K-contig]
// ws[48*576 .. +32*1024) : W2T[n][k] = W2[k][n]                                  [fc2 B, K-contig]
__global__ __launch_bounds__(256) void prep_weights(
    const float* __restrict__ W1, const float* __restrict__ W2,
    const float* __restrict__ Wr, short* __restrict__ ws)
{
  int i = blockIdx.x * 256 + threadIdx.x;
  if (i < 48 * 576) {
    int n = i / 576;
    int k = i - n * 576;
    float v = 0.f;
    if (n < 32) v = W1[k * 32 + n];
    else if (n == 32) v = Wr[k];
    ws[i] = f2bf(v);
  } else {
    int j = i - 48 * 576;
    if (j < 32 * 1024) {
      int n = j >> 5;
      int k = j & 31;
      ws[W2T_OFF + j] = f2bf(W2[k * 1024 + n]);
    }
  }
}

__global__ __launch_bounds__(256, 3) void fclstm_main(
    const float* __restrict__ prev_h, const float* __restrict__ prev_c,
    const float* __restrict__ action, const float* __restrict__ dynamics,
    const float* __restrict__ b1, const float* __restrict__ b2,
    const float* __restrict__ Wr, const float* __restrict__ br,
    const short* __restrict__ wsw,
    float* __restrict__ out_h, float* __restrict__ out_c, float* __restrict__ out_r)
{
  __shared__ short xs[64 * XS_STRIDE];   // 37,888 B : X k-window, bf16
  __shared__ short h1T[64 * H1_STRIDE];  //  5,120 B : h1 row-major for fc2 A-frags

  const int t  = threadIdx.x;
  const int r0 = blockIdx.x * 64;

  const int wid  = t >> 6;
  const int lane = t & 63;
  const int lg   = lane >> 4;   // 16-lane group 0..3
  const int ln   = lane & 15;
  const int m0   = wid << 4;    // this wave's 16-row tile

  // stage one 288-wide k-window of X = [dynamics | action | prev_h] into LDS as bf16
  auto stage = [&](int base) {
    #pragma unroll
    for (int it = 0; it < 18; ++it) {
      int idx = t + 256 * it;          // 64 rows x 72 float4
      int row = idx / 72;
      int c4  = idx - row * 72;
      int col = base + c4 * 4;
      const float* src;
      if (col < 256)      src = dynamics + (r0 + row) * 256 + col;
      else if (col < 320) src = action   + (r0 + row) * 64  + (col - 256);
      else                src = prev_h   + (r0 + row) * 256 + (col - 320);
      float4v v = *(const float4v*)src;
      uint2 p;
      p.x = (uint)(unsigned short)f2bf(v.x) | ((uint)(unsigned short)f2bf(v.y) << 16);
      p.y = (uint)(unsigned short)f2bf(v.z) | ((uint)(unsigned short)f2bf(v.w) << 16);
      *reinterpret_cast<uint2*>(&xs[row * XS_STRIDE + c4 * 4]) = p;
    }
  };

  // ---- fc1: [64x576] @ [576x48] -> h1(32 cols) + reward-x-dot(col 32) ----
  f32x4 acc0 = {0.f,0.f,0.f,0.f};  // cols  0..15
  f32x4 acc1 = {0.f,0.f,0.f,0.f};  // cols 16..31
  f32x4 acc2 = {0.f,0.f,0.f,0.f};  // cols 32..47 (col 32 = x . Wr[0:576])

  const short* xrow = &xs[(m0 + ln) * XS_STRIDE + 8 * lg];
  const short* w1f  = wsw + ln * W1T_K + 8 * lg;

  stage(0);
  __syncthreads();
  #pragma unroll 3
  for (int kk = 0; kk < 288; kk += 32) {
    bf16x8 a  = *(const bf16x8*)(xrow + kk);
    bf16x8 bA = *(const bf16x8*)(w1f + kk);
    bf16x8 bB = *(const bf16x8*)(w1f + 16 * W1T_K + kk);
    bf16x8 bC = *(const bf16x8*)(w1f + 32 * W1T_K + kk);
    acc0 = __builtin_amdgcn_mfma_f32_16x16x32_bf16(a, bA, acc0, 0, 0, 0);
    acc1 = __builtin_amdgcn_mfma_f32_16x16x32_bf16(a, bB, acc1, 0, 0, 0);
    acc2 = __builtin_amdgcn_mfma_f32_16x16x32_bf16(a, bC, acc2, 0, 0, 0);
  }
  __syncthreads();
  stage(288);
  __syncthreads();
  #pragma unroll 3
  for (int kk = 0; kk < 288; kk += 32) {
    bf16x8 a  = *(const bf16x8*)(xrow + kk);
    bf16x8 bA = *(const bf16x8*)(w1f + 288 + kk);
    bf16x8 bB = *(const bf16x8*)(w1f + 16 * W1T_K + 288 + kk);
    bf16x8 bC = *(const bf16x8*)(w1f + 32 * W1T_K + 288 + kk);
    acc0 = __builtin_amdgcn_mfma_f32_16x16x32_bf16(a, bA, acc0, 0, 0, 0);
    acc1 = __builtin_amdgcn_mfma_f32_16x16x32_bf16(a, bB, acc1, 0, 0, 0);
    acc2 = __builtin_amdgcn_mfma_f32_16x16x32_bf16(a, bC, acc2, 0, 0, 0);
  }

  // h1 = tanh(acc + b1), store bf16 row-major [row][k] for fc2 A-frags (wave-local rows)
  {
    float bc0 = b1[ln], bc1 = b1[16 + ln];
    #pragma unroll
    for (int r = 0; r < 4; ++r) {
      int row = m0 + 4 * lg + r;
      h1T[row * H1_STRIDE + ln]      = f2bf(fast_tanh(acc0[r] + bc0));
      h1T[row * H1_STRIDE + 16 + ln] = f2bf(fast_tanh(acc1[r] + bc1));
    }
  }

  // ---- fc2 + LSTM elementwise + reward. Wave owns its 16 rows, loops all 16 col-tiles ----
  bf16x8 af2 = *(const bf16x8*)&h1T[(m0 + ln) * H1_STRIDE + 8 * lg];  // compiler orders vs writes above

  float racc[4] = {0.f, 0.f, 0.f, 0.f};
  const float br0 = br[0];
  const short* w2t = wsw + W2T_OFF;

  #pragma unroll 2
  for (int nt = 0; nt < 16; ++nt) {
    const int nc_ = nt * 16 + ln;                    // col in 0..255
    const short* bb = w2t + nc_ * 32 + 8 * lg;
    bf16x8 bi = *(const bf16x8*)(bb);                // gate i: cols 0..255
    bf16x8 bf_ = *(const bf16x8*)(bb + 256 * 32);    // gate f
    bf16x8 bc_ = *(const bf16x8*)(bb + 512 * 32);    // gate c-hat
    bf16x8 bo = *(const bf16x8*)(bb + 768 * 32);     // gate o
    f32x4 gi = {0.f,0.f,0.f,0.f}, gf = {0.f,0.f,0.f,0.f};
    f32x4 gc = {0.f,0.f,0.f,0.f}, go = {0.f,0.f,0.f,0.f};
    gi = __builtin_amdgcn_mfma_f32_16x16x32_bf16(af2, bi,  gi, 0, 0, 0);
    gf = __builtin_amdgcn_mfma_f32_16x16x32_bf16(af2, bf_, gf, 0, 0, 0);
    gc = __builtin_amdgcn_mfma_f32_16x16x32_bf16(af2, bc_, gc, 0, 0, 0);
    go = __builtin_amdgcn_mfma_f32_16x16x32_bf16(af2, bo,  go, 0, 0, 0);
    float b2i = b2[nc_], b2f = b2[256 + nc_], b2c = b2[512 + nc_], b2o = b2[768 + nc_];
    float wrv = Wr[576 + nc_];
    #pragma unroll
    for (int r = 0; r < 4; ++r) {
      int row = r0 + m0 + 4 * lg + r;
      float pc  = prev_c[row * 256 + nc_];
      float iv  = fast_sigmoid(gi[r] + b2i);
      float fv  = fast_sigmoid(gf[r] + b2f);
      float cv  = fast_tanh(gc[r] + b2c);
      float ov  = fast_sigmoid(go[r] + b2o);
      float ncv = fv * pc + iv * cv;
      float nhv = ov * fast_tanh(ncv);
      out_h[row * 256 + nc_] = nhv;
      out_c[row * 256 + nc_] = ncv;
      racc[r] += nhv * wrv;
    }
  }

  // reward: reduce next_h part across the 16 lanes of each group, add x-part (acc2 col 32) + br
  #pragma unroll
  for (int off = 1; off < 16; off <<= 1) {
    #pragma unroll
    for (int r = 0; r < 4; ++r) racc[r] += __shfl_xor(racc[r], off, 64);
  }
  if (ln == 0) {
    #pragma unroll
    for (int r = 0; r < 4; ++r) {
      float s = acc2[r] + racc[r] + br0;
      out_r[r0 + m0 + 4 * lg + r] = fast_tanh(s);
    }
  }
}

extern "C" void kernel_launch(void* const* d_in, const int* in_sizes, int n_in,
                              void* d_out, int out_size, void* d_ws, size_t ws_size,
                              hipStream_t stream) {
  const float* prev_h   = (const float*)d_in[0];
  const float* prev_c   = (const float*)d_in[1];
  const float* action   = (const float*)d_in[2];
  const float* dynamics = (const float*)d_in[3];
  const float* W1 = (const float*)d_in[4];
  const float* b1 = (const float*)d_in[5];
  const float* W2 = (const float*)d_in[6];
  const float* b2 = (const float*)d_in[7];
  const float* Wr = (const float*)d_in[8];
  const float* br = (const float*)d_in[9];
  short* wsw = (short*)d_ws;   // needs 120,832 bytes

  float* out_h = (float*)d_out;
  float* out_c = out_h + (size_t)65536 * 256;
  float* out_r = out_c + (size_t)65536 * 256;

  prep_weights<<<236, 256, 0, stream>>>(W1, W2, Wr, wsw);
  fclstm_main<<<1024, 256, 0, stream>>>(prev_h, prev_c, action, dynamics,
                                        b1, b2, Wr, br, wsw, out_h, out_c, out_r);
}

// Round 2
// 121.438 us; speedup vs baseline: 1.1996x; 1.1996x over previous
//
#include <hip/hip_runtime.h>
#include <hip/hip_bf16.h>

typedef float f32x4 __attribute__((ext_vector_type(4)));
typedef short bf16x8 __attribute__((ext_vector_type(8)));
typedef float float4v __attribute__((ext_vector_type(4)));

#define H1_STRIDE 40    // 32 + 8 pad
#define W1T_K 576
#define W2T_OFF (48 * 576)

__device__ __forceinline__ short f2bf(float f) {
  __bf16 b = (__bf16)f;
  return __builtin_bit_cast(short, b);
}
__device__ __forceinline__ float fast_sigmoid(float x) {
  return __builtin_amdgcn_rcpf(1.f + __expf(-x));
}
__device__ __forceinline__ float fast_tanh(float x) {
  float e = __expf(2.f * x);
  return 1.f - 2.f * __builtin_amdgcn_rcpf(e + 1.f);  // exact identity; saturates at +-1
}

// ---- prep: bf16 weight layouts in d_ws ----
// ws[0 .. 48*576)        : W1bT[n][k] = (n<32 ? W1[k][n] : n==32 ? Wr[k] : 0)   [fc1 B, K-contig]
// ws[48*576 .. +32*1024) : W2T[n][k] = W2[k][n]                                  [fc2 B, K-contig]
__global__ __launch_bounds__(256) void prep_weights(
    const float* __restrict__ W1, const float* __restrict__ W2,
    const float* __restrict__ Wr, short* __restrict__ ws)
{
  int i = blockIdx.x * 256 + threadIdx.x;
  if (i < 48 * 576) {
    int n = i / 576;
    int k = i - n * 576;
    float v = 0.f;
    if (n < 32) v = W1[k * 32 + n];
    else if (n == 32) v = Wr[k];
    ws[i] = f2bf(v);
  } else {
    int j = i - 48 * 576;
    if (j < 32 * 1024) {
      int n = j >> 5;
      int k = j & 31;
      ws[W2T_OFF + j] = f2bf(W2[k * 1024 + n]);
    }
  }
}

__global__ __launch_bounds__(256, 4) void fclstm_main(
    const float* __restrict__ prev_h, const float* __restrict__ prev_c,
    const float* __restrict__ action, const float* __restrict__ dynamics,
    const float* __restrict__ b1, const float* __restrict__ b2,
    const float* __restrict__ Wr, const float* __restrict__ br,
    const short* __restrict__ wsw,
    float* __restrict__ out_h, float* __restrict__ out_c, float* __restrict__ out_r)
{
  __shared__ short h1T[64 * H1_STRIDE];  // 5,120 B : h1 row-major for fc2 A-frags

  const int t  = threadIdx.x;
  const int r0 = blockIdx.x * 64;

  const int wid  = t >> 6;
  const int lane = t & 63;
  const int lg   = lane >> 4;   // 16-lane group 0..3
  const int ln   = lane & 15;
  const int m0   = wid << 4;    // this wave's 16-row tile

  // ---- fc1: [64x576] @ [576x48] -> h1(32 cols) + reward-x-dot(col 32) ----
  // A-frags loaded straight from global: lane ln owns row m0+ln, k = 32j + 8*lg .. +7.
  // All tensor boundaries (256, 320) are 32-aligned, so each frag is within one tensor.
  f32x4 acc0 = {0.f,0.f,0.f,0.f};  // cols  0..15
  f32x4 acc1 = {0.f,0.f,0.f,0.f};  // cols 16..31
  f32x4 acc2 = {0.f,0.f,0.f,0.f};  // cols 32..47 (col 32 = x . Wr[0:576])

  const int rowA = r0 + m0 + ln;
  const int kb   = 8 * lg;
  const float* dynp = dynamics + rowA * 256 + kb;
  const float* actp = action   + rowA * 64  + kb;
  const float* hp   = prev_h   + rowA * 256 + kb;
  const short* w1f  = wsw + ln * W1T_K + kb;

  auto ldfrag = [&](const float* p) -> bf16x8 {
    float4v v0 = *(const float4v*)(p);
    float4v v1 = *(const float4v*)(p + 4);
    bf16x8 a;
    a[0] = f2bf(v0.x); a[1] = f2bf(v0.y); a[2] = f2bf(v0.z); a[3] = f2bf(v0.w);
    a[4] = f2bf(v1.x); a[5] = f2bf(v1.y); a[6] = f2bf(v1.z); a[7] = f2bf(v1.w);
    return a;
  };

  #pragma unroll
  for (int j = 0; j < 18; ++j) {
    const float* src;
    if (j < 8)       src = dynp + 32 * j;          // dynamics: k 0..255
    else if (j < 10) src = actp + 32 * j - 256;    // action:   k 256..319
    else             src = hp   + 32 * j - 320;    // prev_h:   k 320..575
    bf16x8 a  = ldfrag(src);
    bf16x8 bA = *(const bf16x8*)(w1f + 32 * j);
    bf16x8 bB = *(const bf16x8*)(w1f + 16 * W1T_K + 32 * j);
    bf16x8 bC = *(const bf16x8*)(w1f + 32 * W1T_K + 32 * j);
    acc0 = __builtin_amdgcn_mfma_f32_16x16x32_bf16(a, bA, acc0, 0, 0, 0);
    acc1 = __builtin_amdgcn_mfma_f32_16x16x32_bf16(a, bB, acc1, 0, 0, 0);
    acc2 = __builtin_amdgcn_mfma_f32_16x16x32_bf16(a, bC, acc2, 0, 0, 0);
  }

  // h1 = tanh(acc + b1), store bf16 row-major [row][k] for fc2 A-frags (wave-local rows)
  {
    float bc0 = b1[ln], bc1 = b1[16 + ln];
    #pragma unroll
    for (int r = 0; r < 4; ++r) {
      int row = m0 + 4 * lg + r;
      h1T[row * H1_STRIDE + ln]      = f2bf(fast_tanh(acc0[r] + bc0));
      h1T[row * H1_STRIDE + 16 + ln] = f2bf(fast_tanh(acc1[r] + bc1));
    }
  }
  __syncthreads();

  // ---- fc2 + LSTM elementwise + reward. Wave owns its 16 rows, loops all 16 col-tiles ----
  bf16x8 af2 = *(const bf16x8*)&h1T[(m0 + ln) * H1_STRIDE + 8 * lg];

  float racc[4] = {0.f, 0.f, 0.f, 0.f};
  const float br0 = br[0];
  const short* w2t = wsw + W2T_OFF;
  const int rowb = r0 + m0 + 4 * lg;   // this lane's C-tile row base

  // prev_c software prefetch, distance 1 (the per-tile dependent HBM load was a serial chain)
  float pcA0 = prev_c[(rowb + 0) * 256 + ln];
  float pcA1 = prev_c[(rowb + 1) * 256 + ln];
  float pcA2 = prev_c[(rowb + 2) * 256 + ln];
  float pcA3 = prev_c[(rowb + 3) * 256 + ln];

  #pragma unroll 4
  for (int nt = 0; nt < 16; ++nt) {
    const int nc_ = nt * 16 + ln;                    // col in 0..255
    float pcB0, pcB1, pcB2, pcB3;
    if (nt < 15) {
      pcB0 = prev_c[(rowb + 0) * 256 + nc_ + 16];
      pcB1 = prev_c[(rowb + 1) * 256 + nc_ + 16];
      pcB2 = prev_c[(rowb + 2) * 256 + nc_ + 16];
      pcB3 = prev_c[(rowb + 3) * 256 + nc_ + 16];
    }
    const short* bb = w2t + nc_ * 32 + 8 * lg;
    bf16x8 bi  = *(const bf16x8*)(bb);               // gate i: cols 0..255
    bf16x8 bf_ = *(const bf16x8*)(bb + 256 * 32);    // gate f
    bf16x8 bc_ = *(const bf16x8*)(bb + 512 * 32);    // gate c-hat
    bf16x8 bo  = *(const bf16x8*)(bb + 768 * 32);    // gate o
    f32x4 gi = {0.f,0.f,0.f,0.f}, gf = {0.f,0.f,0.f,0.f};
    f32x4 gc = {0.f,0.f,0.f,0.f}, go = {0.f,0.f,0.f,0.f};
    gi = __builtin_amdgcn_mfma_f32_16x16x32_bf16(af2, bi,  gi, 0, 0, 0);
    gf = __builtin_amdgcn_mfma_f32_16x16x32_bf16(af2, bf_, gf, 0, 0, 0);
    gc = __builtin_amdgcn_mfma_f32_16x16x32_bf16(af2, bc_, gc, 0, 0, 0);
    go = __builtin_amdgcn_mfma_f32_16x16x32_bf16(af2, bo,  go, 0, 0, 0);
    float b2i = b2[nc_], b2f = b2[256 + nc_], b2c = b2[512 + nc_], b2o = b2[768 + nc_];
    float wrv = Wr[576 + nc_];
    float pc_[4] = {pcA0, pcA1, pcA2, pcA3};
    #pragma unroll
    for (int r = 0; r < 4; ++r) {
      int row = rowb + r;
      float iv  = fast_sigmoid(gi[r] + b2i);
      float fv  = fast_sigmoid(gf[r] + b2f);
      float cv  = fast_tanh(gc[r] + b2c);
      float ov  = fast_sigmoid(go[r] + b2o);
      float ncv = fv * pc_[r] + iv * cv;
      float nhv = ov * fast_tanh(ncv);
      out_h[row * 256 + nc_] = nhv;
      out_c[row * 256 + nc_] = ncv;
      racc[r] += nhv * wrv;
    }
    pcA0 = pcB0; pcA1 = pcB1; pcA2 = pcB2; pcA3 = pcB3;
  }

  // reward: reduce next_h part across the 16 lanes of each group, add x-part (acc2 col 32) + br
  #pragma unroll
  for (int off = 1; off < 16; off <<= 1) {
    #pragma unroll
    for (int r = 0; r < 4; ++r) racc[r] += __shfl_xor(racc[r], off, 64);
  }
  if (ln == 0) {
    #pragma unroll
    for (int r = 0; r < 4; ++r) {
      float s = acc2[r] + racc[r] + br0;
      out_r[rowb + r] = fast_tanh(s);
    }
  }
}

extern "C" void kernel_launch(void* const* d_in, const int* in_sizes, int n_in,
                              void* d_out, int out_size, void* d_ws, size_t ws_size,
                              hipStream_t stream) {
  const float* prev_h   = (const float*)d_in[0];
  const float* prev_c   = (const float*)d_in[1];
  const float* action   = (const float*)d_in[2];
  const float* dynamics = (const float*)d_in[3];
  const float* W1 = (const float*)d_in[4];
  const float* b1 = (const float*)d_in[5];
  const float* W2 = (const float*)d_in[6];
  const float* b2 = (const float*)d_in[7];
  const float* Wr = (const float*)d_in[8];
  const float* br = (const float*)d_in[9];
  short* wsw = (short*)d_ws;   // needs 120,832 bytes

  float* out_h = (float*)d_out;
  float* out_c = out_h + (size_t)65536 * 256;
  float* out_r = out_c + (size_t)65536 * 256;

  prep_weights<<<236, 256, 0, stream>>>(W1, W2, Wr, wsw);
  fclstm_main<<<1024, 256, 0, stream>>>(prev_h, prev_c, action, dynamics,
                                        b1, b2, Wr, br, wsw, out_h, out_c, out_r);
}

// Round 3
// 86.664 us; speedup vs baseline: 1.6809x; 1.4012x over previous
//
#include <hip/hip_runtime.h>
#include <hip/hip_bf16.h>

typedef float f32x4 __attribute__((ext_vector_type(4)));
typedef short bf16x8 __attribute__((ext_vector_type(8)));
typedef float float4v __attribute__((ext_vector_type(4)));

#define H1_STRIDE 40    // 32 + 8 pad
#define W1T_K 576
#define W2T_OFF (48 * 576)

__device__ __forceinline__ short f2bf(float f) {
  __bf16 b = (__bf16)f;
  return __builtin_bit_cast(short, b);
}
__device__ __forceinline__ float fast_sigmoid(float x) {
  return __builtin_amdgcn_rcpf(1.f + __expf(-x));
}
__device__ __forceinline__ float fast_tanh(float x) {
  float e = __expf(2.f * x);
  return 1.f - 2.f * __builtin_amdgcn_rcpf(e + 1.f);  // exact identity; saturates at +-1
}

// ---- prep: bf16 weight layouts in d_ws ----
// ws[0 .. 48*576)        : W1bT[n][k] = (n<32 ? W1[k][n] : n==32 ? Wr[k] : 0)   [fc1 B, K-contig]
// ws[48*576 .. +32*1024) : W2T[n][k] = W2[k][n]                                  [fc2 B, K-contig]
__global__ __launch_bounds__(256) void prep_weights(
    const float* __restrict__ W1, const float* __restrict__ W2,
    const float* __restrict__ Wr, short* __restrict__ ws)
{
  int i = blockIdx.x * 256 + threadIdx.x;
  if (i < 48 * 576) {
    int n = i / 576;
    int k = i - n * 576;
    float v = 0.f;
    if (n < 32) v = W1[k * 32 + n];
    else if (n == 32) v = Wr[k];
    ws[i] = f2bf(v);
  } else {
    int j = i - 48 * 576;
    if (j < 32 * 1024) {
      int n = j >> 5;
      int k = j & 31;
      ws[W2T_OFF + j] = f2bf(W2[k * 1024 + n]);
    }
  }
}

__global__ __launch_bounds__(256, 4) void fclstm_main(
    const float* __restrict__ prev_h, const float* __restrict__ prev_c,
    const float* __restrict__ action, const float* __restrict__ dynamics,
    const float* __restrict__ b1, const float* __restrict__ b2,
    const float* __restrict__ Wr, const float* __restrict__ br,
    const short* __restrict__ wsw,
    float* __restrict__ out_h, float* __restrict__ out_c, float* __restrict__ out_r)
{
  __shared__ short h1T[64 * H1_STRIDE];  // 5,120 B : wave-local h1 transpose buffer

  const int t  = threadIdx.x;
  const int r0 = blockIdx.x * 64;

  const int wid  = t >> 6;
  const int lane = t & 63;
  const int lg   = lane >> 4;   // 16-lane group 0..3
  const int ln   = lane & 15;
  const int m0   = wid << 4;    // this wave's 16-row tile
  const int rowb = r0 + m0 + 4 * lg;   // this lane's fc2/C-tile row base

  // ---- prev_c preload, batch 0 (col tiles 0..7): issued NOW so ~900cy HBM
  // latency hides under the whole of fc1. All indices compile-time -> stays in VGPRs.
  float pcA[32];
  #pragma unroll
  for (int q = 0; q < 8; ++q) {
    #pragma unroll
    for (int r = 0; r < 4; ++r)
      pcA[q * 4 + r] = prev_c[(size_t)(rowb + r) * 256 + q * 16 + ln];
  }

  // ---- fc1: [64x576] @ [576x48] -> h1(32 cols) + reward-x-dot(col 32) ----
  f32x4 acc0 = {0.f,0.f,0.f,0.f};  // cols  0..15
  f32x4 acc1 = {0.f,0.f,0.f,0.f};  // cols 16..31
  f32x4 acc2 = {0.f,0.f,0.f,0.f};  // cols 32..47 (col 32 = x . Wr[0:576])

  const int rowA = r0 + m0 + ln;
  const int kb   = 8 * lg;
  const float* dynp = dynamics + rowA * 256 + kb;
  const float* actp = action   + rowA * 64  + kb;
  const float* hp   = prev_h   + rowA * 256 + kb;
  const short* w1f  = wsw + ln * W1T_K + kb;

  auto ldfrag = [&](const float* p) -> bf16x8 {
    float4v v0 = *(const float4v*)(p);
    float4v v1 = *(const float4v*)(p + 4);
    bf16x8 a;
    a[0] = f2bf(v0.x); a[1] = f2bf(v0.y); a[2] = f2bf(v0.z); a[3] = f2bf(v0.w);
    a[4] = f2bf(v1.x); a[5] = f2bf(v1.y); a[6] = f2bf(v1.z); a[7] = f2bf(v1.w);
    return a;
  };

  #pragma unroll
  for (int j = 0; j < 18; ++j) {
    const float* src;
    if (j < 8)       src = dynp + 32 * j;          // dynamics: k 0..255
    else if (j < 10) src = actp + 32 * j - 256;    // action:   k 256..319
    else             src = hp   + 32 * j - 320;    // prev_h:   k 320..575
    bf16x8 a  = ldfrag(src);
    bf16x8 bA = *(const bf16x8*)(w1f + 32 * j);
    bf16x8 bB = *(const bf16x8*)(w1f + 16 * W1T_K + 32 * j);
    bf16x8 bC = *(const bf16x8*)(w1f + 32 * W1T_K + 32 * j);
    acc0 = __builtin_amdgcn_mfma_f32_16x16x32_bf16(a, bA, acc0, 0, 0, 0);
    acc1 = __builtin_amdgcn_mfma_f32_16x16x32_bf16(a, bB, acc1, 0, 0, 0);
    acc2 = __builtin_amdgcn_mfma_f32_16x16x32_bf16(a, bC, acc2, 0, 0, 0);
  }

  // h1 = tanh(acc + b1) -> bf16 row-major, wave-local LDS handoff.
  // Rows m0..m0+15 are written AND read only by this wave: no block barrier
  // needed, just drain this wave's own LDS ops (lockstep within a wave).
  {
    float bc0 = b1[ln], bc1 = b1[16 + ln];
    #pragma unroll
    for (int r = 0; r < 4; ++r) {
      int row = m0 + 4 * lg + r;
      h1T[row * H1_STRIDE + ln]      = f2bf(fast_tanh(acc0[r] + bc0));
      h1T[row * H1_STRIDE + 16 + ln] = f2bf(fast_tanh(acc1[r] + bc1));
    }
  }
  asm volatile("s_waitcnt lgkmcnt(0)" ::: "memory");
  __builtin_amdgcn_sched_barrier(0);
  bf16x8 af2 = *(const bf16x8*)&h1T[(m0 + ln) * H1_STRIDE + 8 * lg];

  // ---- prev_c preload, batch 1 (col tiles 8..15): hides under half-A processing
  float pcB[32];
  #pragma unroll
  for (int q = 0; q < 8; ++q) {
    #pragma unroll
    for (int r = 0; r < 4; ++r)
      pcB[q * 4 + r] = prev_c[(size_t)(rowb + r) * 256 + (q + 8) * 16 + ln];
  }

  // ---- fc2 + LSTM elementwise + reward ----
  float racc[4] = {0.f, 0.f, 0.f, 0.f};
  const float br0 = br[0];
  const short* w2t = wsw + W2T_OFF;

  auto fc2_tile = [&](int nt, float pc0, float pc1, float pc2, float pc3) {
    const int nc_ = nt * 16 + ln;                    // col in 0..255
    const short* bb = w2t + nc_ * 32 + 8 * lg;
    bf16x8 bi  = *(const bf16x8*)(bb);               // gate i: cols 0..255
    bf16x8 bf_ = *(const bf16x8*)(bb + 256 * 32);    // gate f
    bf16x8 bc_ = *(const bf16x8*)(bb + 512 * 32);    // gate c-hat
    bf16x8 bo  = *(const bf16x8*)(bb + 768 * 32);    // gate o
    f32x4 gi = {0.f,0.f,0.f,0.f}, gf = {0.f,0.f,0.f,0.f};
    f32x4 gc = {0.f,0.f,0.f,0.f}, go = {0.f,0.f,0.f,0.f};
    gi = __builtin_amdgcn_mfma_f32_16x16x32_bf16(af2, bi,  gi, 0, 0, 0);
    gf = __builtin_amdgcn_mfma_f32_16x16x32_bf16(af2, bf_, gf, 0, 0, 0);
    gc = __builtin_amdgcn_mfma_f32_16x16x32_bf16(af2, bc_, gc, 0, 0, 0);
    go = __builtin_amdgcn_mfma_f32_16x16x32_bf16(af2, bo,  go, 0, 0, 0);
    float b2i = b2[nc_], b2f = b2[256 + nc_], b2c = b2[512 + nc_], b2o = b2[768 + nc_];
    float wrv = Wr[576 + nc_];
    float pc_[4] = {pc0, pc1, pc2, pc3};
    #pragma unroll
    for (int r = 0; r < 4; ++r) {
      int row = rowb + r;
      float iv  = fast_sigmoid(gi[r] + b2i);
      float fv  = fast_sigmoid(gf[r] + b2f);
      float cv  = fast_tanh(gc[r] + b2c);
      float ov  = fast_sigmoid(go[r] + b2o);
      float ncv = fv * pc_[r] + iv * cv;
      float nhv = ov * fast_tanh(ncv);
      __builtin_nontemporal_store(nhv, &out_h[(size_t)row * 256 + nc_]);
      __builtin_nontemporal_store(ncv, &out_c[(size_t)row * 256 + nc_]);
      racc[r] += nhv * wrv;
    }
  };

  #pragma unroll
  for (int q = 0; q < 8; ++q)
    fc2_tile(q, pcA[q * 4 + 0], pcA[q * 4 + 1], pcA[q * 4 + 2], pcA[q * 4 + 3]);
  #pragma unroll
  for (int q = 0; q < 8; ++q)
    fc2_tile(q + 8, pcB[q * 4 + 0], pcB[q * 4 + 1], pcB[q * 4 + 2], pcB[q * 4 + 3]);

  // reward: reduce next_h part across the 16 lanes of each group, add x-part (acc2 col 32) + br
  #pragma unroll
  for (int off = 1; off < 16; off <<= 1) {
    #pragma unroll
    for (int r = 0; r < 4; ++r) racc[r] += __shfl_xor(racc[r], off, 64);
  }
  if (ln == 0) {
    #pragma unroll
    for (int r = 0; r < 4; ++r) {
      float s = acc2[r] + racc[r] + br0;
      __builtin_nontemporal_store(fast_tanh(s), &out_r[rowb + r]);
    }
  }
}

extern "C" void kernel_launch(void* const* d_in, const int* in_sizes, int n_in,
                              void* d_out, int out_size, void* d_ws, size_t ws_size,
                              hipStream_t stream) {
  const float* prev_h   = (const float*)d_in[0];
  const float* prev_c   = (const float*)d_in[1];
  const float* action   = (const float*)d_in[2];
  const float* dynamics = (const float*)d_in[3];
  const float* W1 = (const float*)d_in[4];
  const float* b1 = (const float*)d_in[5];
  const float* W2 = (const float*)d_in[6];
  const float* b2 = (const float*)d_in[7];
  const float* Wr = (const float*)d_in[8];
  const float* br = (const float*)d_in[9];
  short* wsw = (short*)d_ws;   // needs 120,832 bytes

  float* out_h = (float*)d_out;
  float* out_c = out_h + (size_t)65536 * 256;
  float* out_r = out_c + (size_t)65536 * 256;

  prep_weights<<<236, 256, 0, stream>>>(W1, W2, Wr, wsw);
  fclstm_main<<<1024, 256, 0, stream>>>(prev_h, prev_c, action, dynamics,
                                        b1, b2, Wr, br, wsw, out_h, out_c, out_r);
}